// Round 1
// baseline (632.752 us; speedup 1.0000x reference)
//
#include <hip/hip_runtime.h>
#include <hip/hip_bf16.h>
#include <math.h>

typedef float f32x4 __attribute__((ext_vector_type(4)));
typedef float f32x4u __attribute__((ext_vector_type(4))) __attribute__((aligned(4)));
typedef short s16x8 __attribute__((ext_vector_type(8)));

__device__ __forceinline__ float wave_reduce64(float v) {
#pragma unroll
    for (int m = 32; m > 0; m >>= 1) v += __shfl_xor(v, m, 64);
    return v;
}

__device__ __forceinline__ unsigned short f32_to_bf16_rn(float x) {
    unsigned int u = __float_as_uint(x);
    unsigned int r = (u + 0x7fffu + ((u >> 16) & 1u)) >> 16;
    return (unsigned short)r;
}
__device__ __forceinline__ float bf16_to_f32(unsigned short h) {
    return __uint_as_float(((unsigned int)h) << 16);
}

// ---------------- Kernel A: h0, h1 (tiny MLP head) ----------------
// h0[k][n] = tanh(W1[k][n]*t + B1[k][n]); h1[k][n] = tanh(sum_m W2[k][n][m]*h0[k][m] + B2[k][n])
// 1024 waves, one (k,n) per wave; each lane covers 4 m's (recomputes its h0 slice directly).
__global__ __launch_bounds__(256) void kA(const float* __restrict__ t,
                                          const float* __restrict__ W1, const float* __restrict__ B1,
                                          const float* __restrict__ W2, const float* __restrict__ B2,
                                          float* __restrict__ h1) {
    const int tid = threadIdx.x;
    const int wave = (blockIdx.x << 2) + (tid >> 6);  // 0..1023
    const int lane = tid & 63;
    const int k = wave >> 8, n = wave & 255;
    const float ts = t[0];
    const int m0 = lane << 2;
    f32x4 w1 = *(const f32x4*)(W1 + k * 256 + m0);
    f32x4 b1 = *(const f32x4*)(B1 + k * 256 + m0);
    f32x4 w2 = *(const f32x4*)(W2 + (size_t)(k * 256 + n) * 256 + m0);
    float p = 0.f;
    p += w2.x * tanhf(w1.x * ts + b1.x);
    p += w2.y * tanhf(w1.y * ts + b1.y);
    p += w2.z * tanhf(w1.z * ts + b1.z);
    p += w2.w * tanhf(w1.w * ts + b1.w);
    p = wave_reduce64(p);
    if (lane == 0) h1[k * 256 + n] = tanhf(p + B2[k * 256 + n]);
}

// ---------------- Kernel B: the 540 MB stream (w_in, w_out, b, gate) ----------------
// One wave per output element: 64 lanes x float4 = one 1KB coalesced row, shuffle-reduce.
// Segments: [0,262144) w_in | [262144,524288) w_out | +2048 b | +2048 gate. All divisible
// by 4 waves/block so segment branch is wave-uniform.
__global__ __launch_bounds__(256) void kB(const float* __restrict__ Wwin, const float* __restrict__ bwin,
                                          const float* __restrict__ Wwout, const float* __restrict__ bwout,
                                          const float* __restrict__ Wb, const float* __restrict__ bb,
                                          const float* __restrict__ Wg, const float* __restrict__ bg,
                                          const float* __restrict__ h1,
                                          float* __restrict__ w_in, float* __restrict__ w_out,
                                          unsigned short* __restrict__ w_in_hi, unsigned short* __restrict__ w_in_lo,
                                          unsigned short* __restrict__ w_out_t,
                                          float* __restrict__ b_arr, float* __restrict__ gate) {
    const int lane = threadIdx.x & 63;
    const int wave0 = (blockIdx.x << 2) + (threadIdx.x >> 6);
    const int nwaves = gridDim.x << 2;
    const int m0 = lane << 2;
    for (int r = wave0; r < 528384; r += nwaves) {
        const float* W;
        const float* bias;
        const float* hp;
        int idx, seg;
        if (r < 262144) { seg = 0; idx = r; W = Wwin; bias = bwin; hp = h1; }
        else if (r < 524288) { seg = 1; idx = r - 262144; W = Wwout; bias = bwout; hp = h1 + 256; }
        else if (r < 526336) { seg = 2; idx = r - 524288; W = Wb; bias = bb; hp = h1 + 512; }
        else { seg = 3; idx = r - 526336; W = Wg; bias = bg; hp = h1 + 768; }
        f32x4 wv = *(const f32x4*)(W + (size_t)idx * 256 + m0);
        f32x4 hv = *(const f32x4*)(hp + m0);
        float p = wv.x * hv.x + wv.y * hv.y + wv.z * hv.z + wv.w * hv.w;
        p = wave_reduce64(p);
        if (lane == 0) {
            float v = p + bias[idx];
            if (seg == 0) {
                w_in[idx] = v;
                unsigned short hi = f32_to_bf16_rn(v);
                w_in_hi[idx] = hi;
                w_in_lo[idx] = f32_to_bf16_rn(v - bf16_to_f32(hi));
            } else if (seg == 1) {
                w_out[idx] = v;
                w_out_t[(size_t)(idx & 127) * 2048 + (idx >> 7)] = f32_to_bf16_rn(v);
            } else if (seg == 2) {
                b_arr[idx] = v;
            } else {
                gate[idx] = 1.f / (1.f + __expf(-v));
            }
        }
    }
}

// ---------------- Kernel C: s[f] = dot(w_in[f,:], w_out[f,:]) ----------------
__global__ __launch_bounds__(256) void kC(const float* __restrict__ w_in, const float* __restrict__ w_out,
                                          float* __restrict__ s) {
    const int f = (blockIdx.x << 2) + (threadIdx.x >> 6);  // 0..2047
    const int lane = threadIdx.x & 63;
    float2 a = *(const float2*)(w_in + (size_t)f * 128 + lane * 2);
    float2 b = *(const float2*)(w_out + (size_t)f * 128 + lane * 2);
    float p = a.x * b.x + a.y * b.y;
    p = wave_reduce64(p);
    if (lane == 0) s[f] = p;
}

// ---------------- Kernel D: fused h/g/dz/trace via MFMA ----------------
// 256 blocks x 256 thr. Block owns 32 batch rows. Waves: (w&1)=row-tile (16 rows),
// (w>>1)=f-half (K-split of GEMM2 over f in [0,1024)/[1024,2048)), reduced via LDS at end.
// GEMM1 (K=128): split-bf16 (hi/lo) for ~fp32 precision -> h pre-act in C-layout.
// Epilogue: fast tanh, g=h*gate -> wave-private LDS (A-layout source), trace acc in regs.
// GEMM2 (K=f): straight bf16 from w_out_t (transposed), acc fp32.
__global__ __launch_bounds__(256) void kD(const float* __restrict__ zin,
                                          const unsigned short* __restrict__ w_in_hi,
                                          const unsigned short* __restrict__ w_in_lo,
                                          const unsigned short* __restrict__ w_out_t,
                                          const float* __restrict__ b_arr, const float* __restrict__ gate,
                                          const float* __restrict__ s, float* __restrict__ out) {
    __shared__ __attribute__((aligned(16))) unsigned short g_lds[4][16][72];  // pitch 72 shorts: bank-conflict-free b128 reads
    __shared__ __attribute__((aligned(16))) float red[2][64][36];             // K-split reduction: 32 acc + 4 trace per lane

    const int tid = threadIdx.x;
    const int w = tid >> 6, lane = tid & 63;
    const int q = lane >> 4, lm = lane & 15;
    const int rowtile = w & 1, fhalf = w >> 1;
    const int b0 = blockIdx.x * 32 + rowtile * 16;
    const int brow = b0 + lm;

    // z A-fragments (persistent): 4 k-tiles of K=128, split hi/lo
    s16x8 zh[4], zl[4];
#pragma unroll
    for (int kt = 0; kt < 4; kt++) {
        const float* zp = zin + (size_t)brow * 129 + kt * 32 + q * 8;
        f32x4u z0 = *(const f32x4u*)(zp);
        f32x4u z1 = *(const f32x4u*)(zp + 4);
        float zv[8] = {z0.x, z0.y, z0.z, z0.w, z1.x, z1.y, z1.z, z1.w};
#pragma unroll
        for (int j = 0; j < 8; j++) {
            unsigned short hi = f32_to_bf16_rn(zv[j]);
            zh[kt][j] = (short)hi;
            zl[kt][j] = (short)f32_to_bf16_rn(zv[j] - bf16_to_f32(hi));
        }
    }

    f32x4 acc2[8];
#pragma unroll
    for (int ct = 0; ct < 8; ct++) acc2[ct] = (f32x4){0.f, 0.f, 0.f, 0.f};
    float tr[4] = {0.f, 0.f, 0.f, 0.f};

    for (int ch = 0; ch < 16; ch++) {
        const int f0 = fhalf * 1024 + ch * 64;
        // GEMM1 + epilogue over 4 n-tiles (64 f's)
#pragma unroll
        for (int nt = 0; nt < 4; nt++) {
            const int fc = f0 + nt * 16 + lm;
            const unsigned short* ph = w_in_hi + (size_t)fc * 128;
            const unsigned short* pl = w_in_lo + (size_t)fc * 128;
            f32x4 acc1 = {0.f, 0.f, 0.f, 0.f};
#pragma unroll
            for (int kt = 0; kt < 4; kt++) {
                s16x8 bh = *(const s16x8*)(ph + kt * 32 + q * 8);
                s16x8 bl = *(const s16x8*)(pl + kt * 32 + q * 8);
                acc1 = __builtin_amdgcn_mfma_f32_16x16x32_bf16(zh[kt], bh, acc1, 0, 0, 0);
                acc1 = __builtin_amdgcn_mfma_f32_16x16x32_bf16(zh[kt], bl, acc1, 0, 0, 0);
                acc1 = __builtin_amdgcn_mfma_f32_16x16x32_bf16(zl[kt], bh, acc1, 0, 0, 0);
            }
            const float gv = gate[fc], bv = b_arr[fc], sv = s[fc];
#pragma unroll
            for (int i = 0; i < 4; i++) {
                float pre = acc1[i] + bv;
                float e = __expf(2.f * pre);  // tanh(x) = 1 - 2/(e^{2x}+1); saturates gracefully
                float th = 1.f - 2.f * __builtin_amdgcn_rcpf(e + 1.f);
                float g = th * gv;
                tr[i] += (1.f - th * th) * gv * sv;
                g_lds[w][q * 4 + i][nt * 16 + lm] = f32_to_bf16_rn(g);
            }
        }
        // GEMM2: dz += g @ w_out (this wave's 16 rows, this chunk's 64 f's)
#pragma unroll
        for (int kt2 = 0; kt2 < 2; kt2++) {
            s16x8 af = *(const s16x8*)&g_lds[w][lm][kt2 * 32 + q * 8];
#pragma unroll
            for (int ct = 0; ct < 8; ct++) {
                s16x8 bf = *(const s16x8*)(w_out_t + (size_t)(ct * 16 + lm) * 2048 + f0 + kt2 * 32 + q * 8);
                acc2[ct] = __builtin_amdgcn_mfma_f32_16x16x32_bf16(af, bf, acc2[ct], 0, 0, 0);
            }
        }
    }

    // merge K-split halves
    if (fhalf == 1) {
#pragma unroll
        for (int ct = 0; ct < 8; ct++) *(f32x4*)&red[rowtile][lane][ct * 4] = acc2[ct];
        *(f32x4*)&red[rowtile][lane][32] = (f32x4){tr[0], tr[1], tr[2], tr[3]};
    }
    __syncthreads();
    if (fhalf == 0) {
#pragma unroll
        for (int ct = 0; ct < 8; ct++) {
            f32x4 o = *(const f32x4*)&red[rowtile][lane][ct * 4];
            acc2[ct].x += o.x; acc2[ct].y += o.y; acc2[ct].z += o.z; acc2[ct].w += o.w;
        }
        f32x4 to = *(const f32x4*)&red[rowtile][lane][32];
        tr[0] += to.x; tr[1] += to.y; tr[2] += to.z; tr[3] += to.w;

        const float inv = 1.f / 2048.f;
#pragma unroll
        for (int ct = 0; ct < 8; ct++)
#pragma unroll
            for (int i = 0; i < 4; i++)
                out[(size_t)(b0 + q * 4 + i) * 129 + ct * 16 + lm] = acc2[ct][i] * inv;
        // trace: reduce across the 16 lanes of each quad-row group
#pragma unroll
        for (int i = 0; i < 4; i++) {
            float t2 = tr[i];
            t2 += __shfl_xor(t2, 1, 64);
            t2 += __shfl_xor(t2, 2, 64);
            t2 += __shfl_xor(t2, 4, 64);
            t2 += __shfl_xor(t2, 8, 64);
            if (lm == 0) out[(size_t)(b0 + q * 4 + i) * 129 + 128] = -t2 * inv;
        }
    }
}

extern "C" void kernel_launch(void* const* d_in, const int* in_sizes, int n_in,
                              void* d_out, int out_size, void* d_ws, size_t ws_size,
                              hipStream_t stream) {
    const float* t     = (const float*)d_in[0];
    const float* z     = (const float*)d_in[1];
    const float* W1    = (const float*)d_in[2];
    const float* B1    = (const float*)d_in[3];
    const float* W2    = (const float*)d_in[4];
    const float* B2    = (const float*)d_in[5];
    const float* W3win = (const float*)d_in[6];
    const float* b3win = (const float*)d_in[7];
    const float* W3wo  = (const float*)d_in[8];
    const float* b3wo  = (const float*)d_in[9];
    const float* W3b   = (const float*)d_in[10];
    const float* b3b   = (const float*)d_in[11];
    const float* W3g   = (const float*)d_in[12];
    const float* b3g   = (const float*)d_in[13];
    float* out = (float*)d_out;

    // workspace carve (3.6 MB): floats then bf16 arrays
    float* h1    = (float*)d_ws;        // 1024
    float* w_in  = h1 + 1024;           // 262144
    float* w_out = w_in + 262144;       // 262144
    float* b_arr = w_out + 262144;      // 2048
    float* gate  = b_arr + 2048;        // 2048
    float* s     = gate + 2048;         // 2048
    unsigned short* w_in_hi = (unsigned short*)(s + 2048);  // 262144
    unsigned short* w_in_lo = w_in_hi + 262144;             // 262144
    unsigned short* w_out_t = w_in_lo + 262144;             // 262144 (transposed [c][f])

    kA<<<256, 256, 0, stream>>>(t, W1, B1, W2, B2, h1);
    kB<<<2048, 256, 0, stream>>>(W3win, b3win, W3wo, b3wo, W3b, b3b, W3g, b3g, h1,
                                 w_in, w_out, w_in_hi, w_in_lo, w_out_t, b_arr, gate);
    kC<<<512, 256, 0, stream>>>(w_in, w_out, s);
    kD<<<256, 256, 0, stream>>>(z, w_in_hi, w_in_lo, w_out_t, b_arr, gate, s, out);
    (void)in_sizes; (void)n_in; (void)out_size; (void)ws_size;
}